// Round 8
// baseline (95.895 us; speedup 1.0000x reference)
//
#include <hip/hip_runtime.h>

// NeuralCA: out = clip(x + sum_k sigmoid(10*(conv3x3_k(x) - r_k)) * (p_k - x), 0, 1)
// B=16, H=W=512, NK=16, fp32. VALU-issue-bound (8% HBM, MfmaUtil 0).
// R8: R4 structure EXACTLY (2x4 tile, f2-packed, launch_bounds(256,4)) plus only:
//  (a) -G2 folded into weights on the scalar pipe -> conv accumulates z directly
//      (deletes the z pk-fma; R5-proven piece);
//  (b) batched reciprocal per row: 4 rcp -> 1 rcp + 9 scalar muls + 1 pk-min
//      z<=28 overflow guard (R7-proven numerics: absmax unchanged 0.0039).
// Clean discriminator for trans cost: c_t~16 -> kernel ~25.5us (dur ~86);
// c_t~6 -> neutral (then R4-class is at its issue floor).

#define NK 16
#define BATCH 16
#define H 512
#define W 512
#define G2 14.4269504088896340f   // GAIN(=10) * log2(e)

typedef float f2 __attribute__((ext_vector_type(2)));

#if __has_builtin(__builtin_amdgcn_exp2f)
#define EXP2F(x) __builtin_amdgcn_exp2f(x)
#else
#define EXP2F(x) exp2f(x)
#endif

#if __has_builtin(__builtin_elementwise_fma)
#define FMA2(a, b, c) __builtin_elementwise_fma((a), (b), (c))
#else
#define FMA2(a, b, c) ((a) * (b) + (c))   // fp-contract folds to fma.v2f32
#endif

#if __has_builtin(__builtin_elementwise_min)
#define MIN2(a, b) __builtin_elementwise_min((a), (b))
#else
static __device__ __forceinline__ f2 MIN2(f2 a, f2 b) {
    f2 r; r.x = fminf(a.x, b.x); r.y = fminf(a.y, b.y); return r;
}
#endif

static __device__ __forceinline__ f2 bc2(float s) { f2 r; r.x = s; r.y = s; return r; }

// Constant address space -> guaranteed s_load (SGPR broadcast)
typedef const __attribute__((address_space(4))) float cfloat;

__global__ __launch_bounds__(256, 4) void nca_kernel(
    const float* __restrict__ x,
    const float* __restrict__ kernels,
    const float* __restrict__ reactants,
    const float* __restrict__ products,
    float* __restrict__ out)
{
    // One thread per 2x4 pixel tile. Tiles: 16 * 256 * 128 = 2^19 threads.
    const int idx = blockIdx.x * blockDim.x + threadIdx.x;
    const int w4 = (idx & 127) << 2;        // tile start col (128 tiles/row)
    const int h0 = ((idx >> 7) & 255) << 1; // tile start row
    const int b  = idx >> 15;

    const float* xb = x + (size_t)b * (H * W);

    // 4 rows x 6 cols register window (rows h0-1 .. h0+2, halo 1 each side in w)
    float v[4][6];
#pragma unroll
    for (int r = 0; r < 4; ++r) {
        const int row = h0 + r - 1;
        if (row >= 0 && row < H) {
            const float* xr = xb + row * W;
            const float4 c = *(const float4*)(xr + w4);
            v[r][1] = c.x; v[r][2] = c.y; v[r][3] = c.z; v[r][4] = c.w;
            v[r][0] = (w4 > 0)     ? xr[w4 - 1] : 0.0f;   // zero pad left
            v[r][5] = (w4 + 4 < W) ? xr[w4 + 4] : 0.0f;   // zero pad right
        } else {
#pragma unroll
            for (int c = 0; c < 6; ++c) v[r][c] = 0.0f;   // zero pad top/bottom
        }
    }

    // Shifted float2 slices: sl[r][s] = {v[r][s], v[r][s+1]}, s = 0..4.
    // Output pair g (local cols 2g,2g+1): tap c uses sl[r][2g+c]; center = sl[py+1][2g+1].
    f2 sl[4][5];
#pragma unroll
    for (int r = 0; r < 4; ++r)
#pragma unroll
        for (int s = 0; s < 5; ++s) { sl[r][s].x = v[r][s]; sl[r][s].y = v[r][s + 1]; }

    cfloat* kc = (cfloat*)kernels;
    cfloat* rc = (cfloat*)reactants;
    cfloat* pc = (cfloat*)products;

    // delta = (sum_k sig_k*p_k) - x*(sum_k sig_k)
    f2 s0[2][2], s1[2][2];
#pragma unroll
    for (int py = 0; py < 2; ++py)
#pragma unroll
        for (int g = 0; g < 2; ++g) { s0[py][g] = bc2(0.0f); s1[py][g] = bc2(0.0f); }

    const f2 zcap = bc2(28.0f);   // e = 2^z <= 2^28 so 4-way product < 2^112

#pragma unroll
    for (int k = 0; k < NK; ++k) {
        // -G2 pre-folded on the scalar pipe: conv accumulates z directly.
        // z = c2 + sum gw*x = G2*r_k - G2*N ; e = 2^z = exp(-10*(N - r_k))
        f2 gw[9];
#pragma unroll
        for (int i = 0; i < 9; ++i) gw[i] = bc2(-G2 * kc[k * 9 + i]);
        const f2 c2 = bc2(G2 * rc[k]);
        const f2 pk = bc2(pc[k]);

#pragma unroll
        for (int py = 0; py < 2; ++py) {
            // conv + exp for both pairs of this row
            f2 d[2];                       // d = 1 + e
#pragma unroll
            for (int g = 0; g < 2; ++g) {
                f2 z = c2;
#pragma unroll
                for (int r = 0; r < 3; ++r)
#pragma unroll
                    for (int c = 0; c < 3; ++c)
                        z = FMA2(sl[py + r][2 * g + c], gw[r * 3 + c], z);
                z = MIN2(z, zcap);         // pk min: overflow guard
                f2 e;
                e.x = EXP2F(z.x);          // v_exp_f32
                e.y = EXP2F(z.y);
                d[g] = e + bc2(1.0f);      // pk add (1.0 inline)
            }

            // Batched reciprocal: 1 rcp + 9 muls replaces 4 rcps (R7-proven).
            const float t1 = d[0].x * d[0].y;
            const float t2 = d[1].x * d[1].y;
            const float r4 = __builtin_amdgcn_rcpf(t1 * t2);
            const float r01 = r4 * t2;     // 1/(d0x*d0y)
            const float r23 = r4 * t1;     // 1/(d1x*d1y)
            f2 sig0, sig1;
            sig0.x = r01 * d[0].y;         // 1/d0x
            sig0.y = r01 * d[0].x;         // 1/d0y
            sig1.x = r23 * d[1].y;
            sig1.y = r23 * d[1].x;

            s0[py][0] = s0[py][0] + sig0;          // pk add
            s0[py][1] = s0[py][1] + sig1;
            s1[py][0] = FMA2(sig0, pk, s1[py][0]); // pk fma
            s1[py][1] = FMA2(sig1, pk, s1[py][1]);
        }
    }

#pragma unroll
    for (int py = 0; py < 2; ++py) {
        float4 o;
#pragma unroll
        for (int g = 0; g < 2; ++g) {
            const f2 xv = sl[py + 1][2 * g + 1];   // center pixels of pair
            f2 res = FMA2(-xv, s0[py][g], xv + s1[py][g]);
            res.x = fminf(fmaxf(res.x, 0.0f), 1.0f);
            res.y = fminf(fmaxf(res.y, 0.0f), 1.0f);
            if (g == 0) { o.x = res.x; o.y = res.y; }
            else        { o.z = res.x; o.w = res.y; }
        }
        *(float4*)(out + ((size_t)(b * H + h0 + py) * W + w4)) = o;
    }
}

extern "C" void kernel_launch(void* const* d_in, const int* in_sizes, int n_in,
                              void* d_out, int out_size, void* d_ws, size_t ws_size,
                              hipStream_t stream) {
    const float* x         = (const float*)d_in[0];
    const float* kernels   = (const float*)d_in[1];
    const float* reactants = (const float*)d_in[2];
    const float* products  = (const float*)d_in[3];
    float* out = (float*)d_out;

    const int total_tiles = BATCH * (H / 2) * (W / 4);  // 2^19
    nca_kernel<<<total_tiles / 256, 256, 0, stream>>>(x, kernels, reactants, products, out);
}

// Round 9
// 91.575 us; speedup vs baseline: 1.0472x; 1.0472x over previous
//
#include <hip/hip_runtime.h>

// NeuralCA: out = clip(x + sum_k sigmoid(10*(conv3x3_k(x) - r_k)) * (p_k - x), 0, 1)
// B=16, H=W=512, NK=16, fp32. VALU-issue-bound (8% HBM, MfmaUtil 0).
// R9: R4 math EXACTLY (best: 91.0us; exp+rcp sigmoid, 2x4 tile, (256,4)).
// Cross-round fit (R4..R8): trans ops are cheap (~2-6cyc); every trans-avoidance
// trade lost. MFMA-conv priced out (marshal+butterfly ~21cyc/px > R4's 17).
// Only identified waste left: 18 v_mov weight splats per k (~2-3us). Fix: build
// the {w,w} broadcast as a uniform 64-bit scalar (bit-punned) so it lives in an
// SGPR pair and feeds v_pk_fma_f32's one-scalar-source slot directly.
// Also: build sl[] straight from loads (no v[4][6] intermediate register array).

#define NK 16
#define BATCH 16
#define H 512
#define W 512
#define G2 14.4269504088896340f   // GAIN(=10) * log2(e)

typedef float f2 __attribute__((ext_vector_type(2)));

#if __has_builtin(__builtin_amdgcn_exp2f)
#define EXP2F(x) __builtin_amdgcn_exp2f(x)
#else
#define EXP2F(x) exp2f(x)
#endif

#if __has_builtin(__builtin_elementwise_fma)
#define FMA2(a, b, c) __builtin_elementwise_fma((a), (b), (c))
#else
#define FMA2(a, b, c) ((a) * (b) + (c))   // fp-contract folds to fma.v2f32
#endif

// Uniform {s,s} broadcast built as 64-bit scalar math -> stays in an SGPR pair,
// usable directly as the one scalar source of a VOP3P op (no v_mov splats).
static __device__ __forceinline__ f2 sbc2(float s) {
    unsigned int b = __builtin_bit_cast(unsigned int, s);
    unsigned long long u = ((unsigned long long)b << 32) | (unsigned long long)b;
    return __builtin_bit_cast(f2, u);
}
static __device__ __forceinline__ f2 bc2(float s) { f2 r; r.x = s; r.y = s; return r; }

// Constant address space -> guaranteed s_load (SGPR broadcast)
typedef const __attribute__((address_space(4))) float cfloat;

__global__ __launch_bounds__(256, 4) void nca_kernel(
    const float* __restrict__ x,
    const float* __restrict__ kernels,
    const float* __restrict__ reactants,
    const float* __restrict__ products,
    float* __restrict__ out)
{
    // One thread per 2x4 pixel tile. Tiles: 16 * 256 * 128 = 2^19 threads.
    const int idx = blockIdx.x * blockDim.x + threadIdx.x;
    const int w4 = (idx & 127) << 2;        // tile start col (128 tiles/row)
    const int h0 = ((idx >> 7) & 255) << 1; // tile start row
    const int b  = idx >> 15;

    const float* xb = x + (size_t)b * (H * W);

    // Shifted float2 slices built directly from loads: sl[r][s] = {v[s], v[s+1]},
    // window rows h0-1 .. h0+2, cols w4-1 .. w4+4 (zero-padded at borders).
    // Output pair g (local cols 2g,2g+1): tap c uses sl[r][2g+c]; center = sl[py+1][2g+1].
    f2 sl[4][5];
#pragma unroll
    for (int r = 0; r < 4; ++r) {
        const int row = h0 + r - 1;
        float v0, v1, v2, v3, v4, v5;
        if (row >= 0 && row < H) {
            const float* xr = xb + row * W;
            const float4 c = *(const float4*)(xr + w4);
            v1 = c.x; v2 = c.y; v3 = c.z; v4 = c.w;
            v0 = (w4 > 0)     ? xr[w4 - 1] : 0.0f;   // zero pad left
            v5 = (w4 + 4 < W) ? xr[w4 + 4] : 0.0f;   // zero pad right
        } else {
            v0 = v1 = v2 = v3 = v4 = v5 = 0.0f;      // zero pad top/bottom
        }
        sl[r][0].x = v0; sl[r][0].y = v1;
        sl[r][1].x = v1; sl[r][1].y = v2;
        sl[r][2].x = v2; sl[r][2].y = v3;
        sl[r][3].x = v3; sl[r][3].y = v4;
        sl[r][4].x = v4; sl[r][4].y = v5;
    }

    cfloat* kc = (cfloat*)kernels;
    cfloat* rc = (cfloat*)reactants;
    cfloat* pc = (cfloat*)products;

    // delta = (sum_k sig_k*p_k) - x*(sum_k sig_k)
    f2 s0[2][2], s1[2][2];
#pragma unroll
    for (int py = 0; py < 2; ++py)
#pragma unroll
        for (int g = 0; g < 2; ++g) { s0[py][g] = bc2(0.0f); s1[py][g] = bc2(0.0f); }

#pragma unroll
    for (int k = 0; k < NK; ++k) {
        // All per-k constants as uniform SGPR-pair broadcasts (no VGPR splats).
        f2 gw[9];
#pragma unroll
        for (int i = 0; i < 9; ++i) gw[i] = sbc2(-G2 * kc[k * 9 + i]);
        const f2 c2 = sbc2(G2 * rc[k]);   // z = c2 + sum gw*x ; e = 2^z
        const f2 pk = sbc2(pc[k]);

#pragma unroll
        for (int py = 0; py < 2; ++py) {
#pragma unroll
            for (int g = 0; g < 2; ++g) {
                f2 z = c2;
#pragma unroll
                for (int r = 0; r < 3; ++r)
#pragma unroll
                    for (int c = 0; c < 3; ++c)
                        z = FMA2(sl[py + r][2 * g + c], gw[r * 3 + c], z);
                f2 e;
                e.x = EXP2F(z.x);                    // v_exp_f32
                e.y = EXP2F(z.y);
                const f2 d = e + bc2(1.0f);          // pk add (inline 1.0)
                f2 sig;
                sig.x = __builtin_amdgcn_rcpf(d.x);  // v_rcp_f32
                sig.y = __builtin_amdgcn_rcpf(d.y);
                s0[py][g] = s0[py][g] + sig;         // pk add
                s1[py][g] = FMA2(sig, pk, s1[py][g]); // pk fma (pk in SGPR pair)
            }
        }
    }

#pragma unroll
    for (int py = 0; py < 2; ++py) {
        float4 o;
#pragma unroll
        for (int g = 0; g < 2; ++g) {
            const f2 xv = sl[py + 1][2 * g + 1];     // center pixels of pair
            f2 res = FMA2(-xv, s0[py][g], xv + s1[py][g]);
            res.x = fminf(fmaxf(res.x, 0.0f), 1.0f);
            res.y = fminf(fmaxf(res.y, 0.0f), 1.0f);
            if (g == 0) { o.x = res.x; o.y = res.y; }
            else        { o.z = res.x; o.w = res.y; }
        }
        *(float4*)(out + ((size_t)(b * H + h0 + py) * W + w4)) = o;
    }
}

extern "C" void kernel_launch(void* const* d_in, const int* in_sizes, int n_in,
                              void* d_out, int out_size, void* d_ws, size_t ws_size,
                              hipStream_t stream) {
    const float* x         = (const float*)d_in[0];
    const float* kernels   = (const float*)d_in[1];
    const float* reactants = (const float*)d_in[2];
    const float* products  = (const float*)d_in[3];
    float* out = (float*)d_out;

    const int total_tiles = BATCH * (H / 2) * (W / 4);  // 2^19
    nca_kernel<<<total_tiles / 256, 256, 0, stream>>>(x, kernels, reactants, products, out);
}